// Round 1
// baseline (2938.514 us; speedup 1.0000x reference)
//
#include <hip/hip_runtime.h>

// ---------------------------------------------------------------------------
// ERC GNN forward: 1 GAT branch + 3 GCN branches + self perceptron + classifier
// fp32 throughout (round 1: correctness-first, CSR-based aggregation, no atomic
// fp adds in segment_sum).
// ---------------------------------------------------------------------------

constexpr int D      = 256;
constexpr int NHEAD  = 8;
constexpr int DHEAD  = 32;
constexpr int NCLS   = 7;
constexpr float BN_EPS = 1e-9f;

// ---------------- GEMM: C[M,256] = (A[M,256] @ B'[256,256]) + bias ----------
// Generic B addressing: element (d, j) at B[(j>>5)*sH + d*sD + (j&31)]
//   - plain row-major [256,256]: sH=32,  sD=256
//   - GAT [H,256,32] layout:     sH=8192, sD=32
constexpr int BM = 128, BN = 64, BK = 16;

__launch_bounds__(256)
__global__ void k_gemm(const float* __restrict__ A, const float* __restrict__ B,
                       const float* __restrict__ bias, float* __restrict__ C,
                       int M, int sH, int sD, int doRelu)
{
  __shared__ float As[BK][BM + 2];
  __shared__ float Bs[BK][BN + 4];
  const int t  = threadIdx.x;
  const int tx = t & 15, ty = t >> 4;
  const int bm = blockIdx.x * BM;
  const int bn = blockIdx.y * BN;
  float acc[8][4] = {};

  for (int k0 = 0; k0 < D; k0 += BK) {
    // A tile: 128 rows x 16 k, 8 elems/thread (2x float4)
    {
      const int r  = t >> 1;
      const int kk = (t & 1) * 8;
      const int row = bm + r;
      float4 a0 = make_float4(0.f, 0.f, 0.f, 0.f), a1 = a0;
      if (row < M) {
        const float* p = A + (size_t)row * D + k0 + kk;
        a0 = *(const float4*)(p);
        a1 = *(const float4*)(p + 4);
      }
      As[kk + 0][r] = a0.x; As[kk + 1][r] = a0.y;
      As[kk + 2][r] = a0.z; As[kk + 3][r] = a0.w;
      As[kk + 4][r] = a1.x; As[kk + 5][r] = a1.y;
      As[kk + 6][r] = a1.z; As[kk + 7][r] = a1.w;
    }
    // B tile: 16 k x 64 cols, 4 elems/thread (scalar loads: GAT layout breaks
    // contiguity at 32-col boundaries; B is tiny and L2-resident anyway)
    {
      const int dd = t >> 4;
      const int j  = (t & 15) * 4;
#pragma unroll
      for (int i = 0; i < 4; ++i) {
        const int jg = bn + j + i;
        Bs[dd][j + i] = B[(size_t)(jg >> 5) * sH + (size_t)(k0 + dd) * sD + (jg & 31)];
      }
    }
    __syncthreads();
#pragma unroll
    for (int kk = 0; kk < BK; ++kk) {
      float a[8], b[4];
#pragma unroll
      for (int i = 0; i < 8; ++i) a[i] = As[kk][ty * 8 + i];
#pragma unroll
      for (int j = 0; j < 4; ++j) b[j] = Bs[kk][tx * 4 + j];
#pragma unroll
      for (int i = 0; i < 8; ++i)
#pragma unroll
        for (int j = 0; j < 4; ++j)
          acc[i][j] = fmaf(a[i], b[j], acc[i][j]);
    }
    __syncthreads();
  }

  const float4 b4 = *(const float4*)(bias + bn + tx * 4);
#pragma unroll
  for (int i = 0; i < 8; ++i) {
    const int row = bm + ty * 8 + i;
    if (row < M) {
      float4 o;
      o.x = acc[i][0] + b4.x;
      o.y = acc[i][1] + b4.y;
      o.z = acc[i][2] + b4.z;
      o.w = acc[i][3] + b4.w;
      if (doRelu) {
        o.x = fmaxf(o.x, 0.f); o.y = fmaxf(o.y, 0.f);
        o.z = fmaxf(o.z, 0.f); o.w = fmaxf(o.w, 0.f);
      }
      *(float4*)(C + (size_t)row * D + bn + tx * 4) = o;
    }
  }
}

// ---------------- CSR build --------------------------------------------------
__global__ void k_count(const int* __restrict__ rows, int* __restrict__ cnt, int E)
{
  int e = blockIdx.x * 256 + threadIdx.x;
  if (e < E) atomicAdd(&cnt[rows[e]], 1);
}

__global__ void k_scan(const int* __restrict__ cnt, int* __restrict__ rowptr, int n)
{
  __shared__ int buf[1024];
  __shared__ int carry_s;
  const int t = threadIdx.x;
  if (t == 0) carry_s = 0;
  __syncthreads();
  for (int base = 0; base < n; base += 1024) {
    const int i = base + t;
    buf[t] = (i < n) ? cnt[i] : 0;
    __syncthreads();
    for (int off = 1; off < 1024; off <<= 1) {
      int x = (t >= off) ? buf[t - off] : 0;
      __syncthreads();
      buf[t] += x;
      __syncthreads();
    }
    const int carry = carry_s;
    if (i < n) rowptr[i + 1] = carry + buf[t];
    __syncthreads();
    if (t == 1023) carry_s = carry + buf[1023];
    __syncthreads();
  }
  if (t == 0) rowptr[0] = 0;
}

__global__ void k_scatter(const int* __restrict__ rows, const int* __restrict__ cols,
                          const float* __restrict__ vals,
                          const int* __restrict__ rowptr, int* __restrict__ fill,
                          int* __restrict__ colS, float* __restrict__ valS, int E)
{
  int e = blockIdx.x * 256 + threadIdx.x;
  if (e < E) {
    const int r = rows[e];
    const int p = rowptr[r] + atomicAdd(&fill[r], 1);
    colS[p] = cols[e];
    valS[p] = vals[e];
  }
}

// ---------------- GAT attention scalars -------------------------------------
// att_s[n,h] = leaky(sum_k f_self[n,h,k]*a_s[h,k]); att_n likewise (from f_self)
__global__ void k_att(const float* __restrict__ fself, const float* __restrict__ a_s,
                      const float* __restrict__ a_n, float* __restrict__ attS,
                      float* __restrict__ attN, int N)
{
  const int n = blockIdx.x * 4 + (threadIdx.x >> 6);
  if (n >= N) return;
  const int lane = threadIdx.x & 63;
  const float4 v  = *(const float4*)(fself + (size_t)n * D + lane * 4);
  const float4 as = *(const float4*)(a_s + lane * 4);
  const float4 an = *(const float4*)(a_n + lane * 4);
  float ps = v.x * as.x + v.y * as.y + v.z * as.z + v.w * as.w;
  float pn = v.x * an.x + v.y * an.y + v.z * an.z + v.w * an.w;
#pragma unroll
  for (int off = 4; off >= 1; off >>= 1) {
    ps += __shfl_down(ps, off, 8);
    pn += __shfl_down(pn, off, 8);
  }
  if ((lane & 7) == 0) {
    const int h = lane >> 3;
    attS[(size_t)n * NHEAD + h] = (ps > 0.f) ? ps : 0.2f * ps;
    attN[(size_t)n * NHEAD + h] = (pn > 0.f) ? pn : 0.2f * pn;
  }
}

// ---------------- Aggregations (one wave per node, CSR) ---------------------
__global__ void k_gat_agg(const float* __restrict__ fneigh,
                          const float* __restrict__ attS, const float* __restrict__ attN,
                          const int* __restrict__ rowptr, const int* __restrict__ colS,
                          const float* __restrict__ valS,
                          float* __restrict__ out, int N)
{
  const int n = blockIdx.x * 4 + (threadIdx.x >> 6);
  if (n >= N) return;
  const int lane = threadIdx.x & 63;
  const int head = lane >> 3;                 // lane*4 .. lane*4+3 stay in one head
  const float as = attS[(size_t)n * NHEAD + head];
  float4 acc = make_float4(0.f, 0.f, 0.f, 0.f);
  const int s = rowptr[n], e = rowptr[n + 1];
  for (int p = s; p < e; ++p) {
    const int c   = colS[p];
    const float v = valS[p];
    const float an = attN[(size_t)c * NHEAD + head];
    const float coef = (as + an) * v;
    const float4 f = *(const float4*)(fneigh + (size_t)c * D + lane * 4);
    acc.x = fmaf(coef, f.x, acc.x);
    acc.y = fmaf(coef, f.y, acc.y);
    acc.z = fmaf(coef, f.z, acc.z);
    acc.w = fmaf(coef, f.w, acc.w);
  }
  *(float4*)(out + (size_t)n * D + lane * 4) = acc;   // no relu (BN directly)
}

__global__ void k_gcn_agg(const float* __restrict__ Hm,
                          const int* __restrict__ rowptr, const int* __restrict__ colS,
                          const float* __restrict__ valS,
                          float* __restrict__ out, int N)
{
  const int n = blockIdx.x * 4 + (threadIdx.x >> 6);
  if (n >= N) return;
  const int lane = threadIdx.x & 63;
  float4 acc = make_float4(0.f, 0.f, 0.f, 0.f);
  const int s = rowptr[n], e = rowptr[n + 1];
  for (int p = s; p < e; ++p) {
    const int c   = colS[p];
    const float v = valS[p];
    const float4 h = *(const float4*)(Hm + (size_t)c * D + lane * 4);
    acc.x = fmaf(v, h.x, acc.x);
    acc.y = fmaf(v, h.y, acc.y);
    acc.z = fmaf(v, h.z, acc.z);
    acc.w = fmaf(v, h.w, acc.w);
  }
  float4 o;                                    // relu(agg) before BN
  o.x = fmaxf(acc.x, 0.f); o.y = fmaxf(acc.y, 0.f);
  o.z = fmaxf(acc.z, 0.f); o.w = fmaxf(acc.w, 0.f);
  *(float4*)(out + (size_t)n * D + lane * 4) = o;
}

// ---------------- BatchNorm (training-mode, biased var, gamma=1 beta=0) -----
__global__ void k_bn_stats(const float* __restrict__ X, float* __restrict__ sums, int M)
{
  const int j = threadIdx.x;   // 256 columns
  float s = 0.f, q = 0.f;
  for (int r = blockIdx.x; r < M; r += gridDim.x) {
    const float v = X[(size_t)r * D + j];
    s += v;
    q = fmaf(v, v, q);
  }
  atomicAdd(&sums[j], s);
  atomicAdd(&sums[D + j], q);
}

__global__ void k_bn_fin(float* __restrict__ s, int M)
{
  const int j = threadIdx.x;
  const float mu  = s[j] / (float)M;
  const float var = s[D + j] / (float)M - mu * mu;
  s[j]     = mu;
  s[D + j] = rsqrtf(var + BN_EPS);
}

__global__ void k_bn_norm(float* __restrict__ X, const float* __restrict__ s, int M)
{
  const int idx = blockIdx.x * 256 + threadIdx.x;   // one float4 per thread
  if (idx >= M * (D / 4)) return;
  const int j = (idx & 63) * 4;
  float4 x = *(float4*)(X + (size_t)idx * 4);
  x.x = (x.x - s[j + 0]) * s[D + j + 0];
  x.y = (x.y - s[j + 1]) * s[D + j + 1];
  x.z = (x.z - s[j + 2]) * s[D + j + 2];
  x.w = (x.w - s[j + 3]) * s[D + j + 3];
  *(float4*)(X + (size_t)idx * 4) = x;
}

// ---------------- Classifier ------------------------------------------------
__global__ void k_init_out(float* __restrict__ out, const float* __restrict__ cls_b, int n)
{
  const int i = blockIdx.x * 256 + threadIdx.x;
  if (i < n) out[i] = cls_b[i % NCLS];
}

// out[n, 0..6] += F[n, :] @ cls_W[baseRow .. baseRow+255, :]
__global__ void k_classifier(const float* __restrict__ F, const float* __restrict__ W,
                             float* __restrict__ out, int N, int baseRow)
{
  const int n = blockIdx.x * 4 + (threadIdx.x >> 6);
  if (n >= N) return;
  const int lane = threadIdx.x & 63;
  const float4 f = *(const float4*)(F + (size_t)n * D + lane * 4);
  const float* Wr = W + (size_t)(baseRow + lane * 4) * NCLS;
  float p[NCLS];
#pragma unroll
  for (int c = 0; c < NCLS; ++c)
    p[c] = f.x * Wr[c] + f.y * Wr[NCLS + c] + f.z * Wr[2 * NCLS + c] + f.w * Wr[3 * NCLS + c];
#pragma unroll
  for (int off = 32; off >= 1; off >>= 1)
#pragma unroll
    for (int c = 0; c < NCLS; ++c)
      p[c] += __shfl_down(p[c], off);
  if (lane == 0) {
    float* o = out + (size_t)n * NCLS;
#pragma unroll
    for (int c = 0; c < NCLS; ++c) o[c] += p[c];
  }
}

// ---------------------------------------------------------------------------
extern "C" void kernel_launch(void* const* d_in, const int* in_sizes, int n_in,
                              void* d_out, int out_size, void* d_ws, size_t ws_size,
                              hipStream_t stream)
{
  const float* f_in   = (const float*)d_in[0];
  const int*   erow   = (const int*)d_in[1];
  const int*   ecol   = (const int*)d_in[2];
  const float* eval   = (const float*)d_in[3];
  const float* gat_Ws = (const float*)d_in[4];
  const float* gat_bs = (const float*)d_in[5];
  const float* gat_Wn = (const float*)d_in[6];
  const float* gat_bn = (const float*)d_in[7];
  const float* gat_as = (const float*)d_in[8];
  const float* gat_an = (const float*)d_in[9];
  const float* gcn_W  = (const float*)d_in[10];
  const float* gcn_b  = (const float*)d_in[11];
  const float* self_W = (const float*)d_in[12];
  const float* self_b = (const float*)d_in[13];
  const float* cls_W  = (const float*)d_in[14];
  const float* cls_b  = (const float*)d_in[15];
  float* out = (float*)d_out;

  const int N = in_sizes[0] / D;     // 50000
  const int E = in_sizes[1] / 4;     // 400000 (4 adjacencies)
  const size_t ND = (size_t)N * D;

  // ---- workspace carve-up (fp32) ----
  float* bufA  = (float*)d_ws;
  float* bufB  = bufA + ND;
  float* bufC  = bufB + ND;
  float* attS  = bufC + ND;           // N*8
  float* attN  = attS + (size_t)N * NHEAD;
  float* bnbuf = attN + (size_t)N * NHEAD;   // 512
  int*   cnt    = (int*)(bnbuf + 2 * D);
  int*   rowptr = cnt + N;
  int*   colS   = rowptr + (N + 1);
  float* valS   = (float*)(colS + E);

  const dim3 gemm_grid((N + BM - 1) / BM, D / BN);
  const int  nb4   = (N + 3) / 4;           // wave-per-node kernels
  const int  ebks  = (E + 255) / 256;
  const int  nrm   = (N * (D / 4) + 255) / 256;

  auto build_csr = [&](int a) {
    hipMemsetAsync(cnt, 0, (size_t)N * sizeof(int), stream);
    k_count<<<ebks, 256, 0, stream>>>(erow + (size_t)a * E, cnt, E);
    k_scan<<<1, 1024, 0, stream>>>(cnt, rowptr, N);
    hipMemsetAsync(cnt, 0, (size_t)N * sizeof(int), stream);
    k_scatter<<<ebks, 256, 0, stream>>>(erow + (size_t)a * E, ecol + (size_t)a * E,
                                        eval + (size_t)a * E, rowptr, cnt, colS, valS, E);
  };

  auto bn = [&](float* X) {
    hipMemsetAsync(bnbuf, 0, 2 * D * sizeof(float), stream);
    k_bn_stats<<<512, 256, 0, stream>>>(X, bnbuf, N);
    k_bn_fin<<<1, D, 0, stream>>>(bnbuf, N);
    k_bn_norm<<<nrm, 256, 0, stream>>>(X, bnbuf, N);
  };

  // init output with classifier bias; branches accumulate into it
  k_init_out<<<(N * NCLS + 255) / 256, 256, 0, stream>>>(out, cls_b, N * NCLS);

  // ===================== GAT branch (adjacency 0) ==========================
  build_csr(0);
  {
    const size_t WOFF = (size_t)NHEAD * D * DHEAD;   // 65536 per layer
    // layer 0: f = f_in -> out in bufA
    k_gemm<<<gemm_grid, 256, 0, stream>>>(f_in, gat_Ws, gat_bs, bufA, N, 8192, 32, 1);
    k_att<<<nb4, 256, 0, stream>>>(bufA, gat_as, gat_an, attS, attN, N);
    k_gemm<<<gemm_grid, 256, 0, stream>>>(f_in, gat_Wn, gat_bn, bufB, N, 8192, 32, 1);
    k_gat_agg<<<nb4, 256, 0, stream>>>(bufB, attS, attN, rowptr, colS, valS, bufA, N);
    bn(bufA);
    // layer 1: f = bufA -> out in bufC
    k_gemm<<<gemm_grid, 256, 0, stream>>>(bufA, gat_Ws + WOFF, gat_bs + D, bufC, N, 8192, 32, 1);
    k_att<<<nb4, 256, 0, stream>>>(bufC, gat_as + D, gat_an + D, attS, attN, N);
    k_gemm<<<gemm_grid, 256, 0, stream>>>(bufA, gat_Wn + WOFF, gat_bn + D, bufB, N, 8192, 32, 1);
    k_gat_agg<<<nb4, 256, 0, stream>>>(bufB, attS, attN, rowptr, colS, valS, bufC, N);
    bn(bufC);
    k_classifier<<<nb4, 256, 0, stream>>>(bufC, cls_W, out, N, 0);
  }

  // ===================== 3 GCN branches (adjacency 1..3) ===================
  for (int g = 0; g < 3; ++g) {
    build_csr(g + 1);
    const float* Wg = gcn_W + (size_t)g * 2 * D * D;
    const float* bg = gcn_b + (size_t)g * 2 * D;
    // layer 0
    k_gemm<<<gemm_grid, 256, 0, stream>>>(f_in, Wg, bg, bufA, N, 32, 256, 0);
    k_gcn_agg<<<nb4, 256, 0, stream>>>(bufA, rowptr, colS, valS, bufB, N);
    bn(bufB);
    // layer 1
    k_gemm<<<gemm_grid, 256, 0, stream>>>(bufB, Wg + (size_t)D * D, bg + D, bufA, N, 32, 256, 0);
    k_gcn_agg<<<nb4, 256, 0, stream>>>(bufA, rowptr, colS, valS, bufC, N);
    bn(bufC);
    k_classifier<<<nb4, 256, 0, stream>>>(bufC, cls_W, out, N, (1 + g) * D);
  }

  // ===================== self perceptron ===================================
  k_gemm<<<gemm_grid, 256, 0, stream>>>(f_in, self_W, self_b, bufA, N, 32, 256, 1);
  bn(bufA);
  k_classifier<<<nb4, 256, 0, stream>>>(bufA, cls_W, out, N, 4 * D);
}

// Round 2
// 1637.405 us; speedup vs baseline: 1.7946x; 1.7946x over previous
//
#include <hip/hip_runtime.h>

// ---------------------------------------------------------------------------
// ERC GNN forward — round 2: bf16 MFMA GEMMs (16x16x32), all-bf16 activations,
// batched CSR build, fused BN finalize+normalize(+bf16 cast).
// ---------------------------------------------------------------------------

constexpr int D     = 256;
constexpr int NHEAD = 8;
constexpr int NCLS  = 7;
constexpr float BN_EPS = 1e-9f;

typedef short  s16x8 __attribute__((ext_vector_type(8)));
typedef float  f32x4 __attribute__((ext_vector_type(4)));

__device__ __forceinline__ unsigned short f2bf(float f) {
  unsigned int u = __builtin_bit_cast(unsigned int, f);
  u += 0x7FFFu + ((u >> 16) & 1u);          // round-to-nearest-even
  return (unsigned short)(u >> 16);
}
__device__ __forceinline__ float bf2f(unsigned short h) {
  unsigned int u = ((unsigned int)h) << 16;
  return __builtin_bit_cast(float, u);
}

// ---------------- bf16 MFMA GEMM: C[M,256] = A[M,256] @ Wt^T + bias ---------
// A: bf16 row-major [M,256]. Wt: bf16 [256 cols][256 k] (pre-transposed).
// 128x128 tile, 4 waves, each wave 64x64 via 4x4 grid of 16x16x32 MFMA.
constexpr int LDT = 40;   // padded LDS row stride (elems): breaks 8-way conflicts

__launch_bounds__(256)
__global__ void k_gemm_mfma(const unsigned short* __restrict__ A,
                            const unsigned short* __restrict__ Wt,
                            const float* __restrict__ bias,
                            unsigned short* __restrict__ C,
                            int M, int doRelu)
{
  __shared__ unsigned short As[128 * LDT];
  __shared__ unsigned short Bs[128 * LDT];
  const int t    = threadIdx.x;
  const int wave = t >> 6, lane = t & 63;
  const int quad = lane >> 4, l16 = lane & 15;
  const int wm = (wave & 1) * 64, wn = (wave >> 1) * 64;
  const int bm = blockIdx.x * 128, bn = blockIdx.y * 128;

  f32x4 acc[4][4] = {};

  // staging: 512 segments of 8 bf16 (16B); thread handles seg t and t+256
  const int r0 = t >> 2,          ko0 = (t & 3) * 8;
  const int r1 = (t + 256) >> 2,  ko1 = ((t + 256) & 3) * 8;

  for (int k0 = 0; k0 < D; k0 += 32) {
    {
      const int ga0 = min(bm + r0, M - 1);
      const int ga1 = min(bm + r1, M - 1);
      *(uint4*)(&As[r0 * LDT + ko0]) = *(const uint4*)(A + (size_t)ga0 * D + k0 + ko0);
      *(uint4*)(&As[r1 * LDT + ko1]) = *(const uint4*)(A + (size_t)ga1 * D + k0 + ko1);
      *(uint4*)(&Bs[r0 * LDT + ko0]) = *(const uint4*)(Wt + (size_t)(bn + r0) * D + k0 + ko0);
      *(uint4*)(&Bs[r1 * LDT + ko1]) = *(const uint4*)(Wt + (size_t)(bn + r1) * D + k0 + ko1);
    }
    __syncthreads();
    s16x8 af[4], bf[4];
#pragma unroll
    for (int mi = 0; mi < 4; ++mi)
      af[mi] = *(const s16x8*)(&As[(wm + mi * 16 + l16) * LDT + quad * 8]);
#pragma unroll
    for (int nj = 0; nj < 4; ++nj)
      bf[nj] = *(const s16x8*)(&Bs[(wn + nj * 16 + l16) * LDT + quad * 8]);
#pragma unroll
    for (int mi = 0; mi < 4; ++mi)
#pragma unroll
      for (int nj = 0; nj < 4; ++nj)
        acc[mi][nj] = __builtin_amdgcn_mfma_f32_16x16x32_bf16(af[mi], bf[nj], acc[mi][nj], 0, 0, 0);
    __syncthreads();
  }

  // epilogue: C/D layout col=lane&15, row=quad*4+reg (m89-verified)
#pragma unroll
  for (int nj = 0; nj < 4; ++nj) {
    const int col = bn + wn + nj * 16 + l16;
    const float bv = bias[col];
#pragma unroll
    for (int mi = 0; mi < 4; ++mi) {
#pragma unroll
      for (int r = 0; r < 4; ++r) {
        const int row = bm + wm + mi * 16 + quad * 4 + r;
        if (row < M) {
          float v = acc[mi][nj][r] + bv;
          if (doRelu) v = fmaxf(v, 0.f);
          C[(size_t)row * D + col] = f2bf(v);
        }
      }
    }
  }
}

// ---------------- conversions -----------------------------------------------
__global__ void k_cvt(const float* __restrict__ src, unsigned short* __restrict__ dst, int n8)
{
  const int i = blockIdx.x * 256 + threadIdx.x;
  if (i >= n8) return;
  const float4 a = *(const float4*)(src + (size_t)i * 8);
  const float4 b = *(const float4*)(src + (size_t)i * 8 + 4);
  uint4 o;
  o.x = (unsigned)f2bf(a.x) | ((unsigned)f2bf(a.y) << 16);
  o.y = (unsigned)f2bf(a.z) | ((unsigned)f2bf(a.w) << 16);
  o.z = (unsigned)f2bf(b.x) | ((unsigned)f2bf(b.y) << 16);
  o.w = (unsigned)f2bf(b.z) | ((unsigned)f2bf(b.w) << 16);
  *(uint4*)(dst + (size_t)i * 8) = o;
}

// Wt[m][j][d]: 11 weight matrices transposed to [col][k] bf16
__global__ void k_cvt_w(const float* __restrict__ gat_Ws, const float* __restrict__ gat_Wn,
                        const float* __restrict__ gcn_W, const float* __restrict__ self_W,
                        unsigned short* __restrict__ Wt)
{
  const int m = blockIdx.x >> 8, j = blockIdx.x & 255, d = threadIdx.x;
  float v;
  if (m < 4) {
    const int l = m >> 1;
    const float* W = (m & 1) ? gat_Wn : gat_Ws;          // [L,H,D,DH]
    v = W[(((size_t)l * NHEAD + (j >> 5)) * D + d) * 32 + (j & 31)];
  } else if (m < 10) {
    v = gcn_W[((size_t)(m - 4) * D + d) * D + j];         // [3*L,D,D]
  } else {
    v = self_W[(size_t)d * D + j];
  }
  Wt[((size_t)m * D + j) * D + d] = f2bf(v);
}

// ---------------- batched CSR build (4 adjacencies) --------------------------
__global__ void k_count(const int* __restrict__ rows, int* __restrict__ cnt, int E4, int E, int N)
{
  const int i = blockIdx.x * 256 + threadIdx.x;
  if (i < E4) atomicAdd(&cnt[(i / E) * N + rows[i]], 1);
}

__global__ void k_scan_blk(const int* __restrict__ in, int* __restrict__ scanTmp,
                           int* __restrict__ blkSum, int n)
{
  __shared__ int buf[256];
  const int t = threadIdx.x, i = blockIdx.x * 256 + t;
  const int v = (i < n) ? in[i] : 0;
  buf[t] = v; __syncthreads();
  for (int off = 1; off < 256; off <<= 1) {
    const int x = (t >= off) ? buf[t - off] : 0;
    __syncthreads();
    buf[t] += x; __syncthreads();
  }
  if (i < n) scanTmp[i] = buf[t];            // inclusive within block
  if (t == 255) blkSum[blockIdx.x] = buf[255];
}

__global__ void k_scan_top(int* __restrict__ blkSum, int G)
{
  __shared__ int buf[1024];
  const int t = threadIdx.x;
  const int v = (t < G) ? blkSum[t] : 0;
  buf[t] = v; __syncthreads();
  for (int off = 1; off < 1024; off <<= 1) {
    const int x = (t >= off) ? buf[t - off] : 0;
    __syncthreads();
    buf[t] += x; __syncthreads();
  }
  if (t < G) blkSum[t] = buf[t] - v;         // exclusive block offsets
}

__global__ void k_scan_fin(const int* __restrict__ scanTmp, const int* __restrict__ blkOff,
                           int* __restrict__ rowptr, int n)
{
  const int i = blockIdx.x * 256 + threadIdx.x;
  if (i < n) rowptr[i + 1] = scanTmp[i] + blkOff[blockIdx.x];
  if (i == 0) rowptr[0] = 0;
}

__global__ void k_scatter(const int* __restrict__ rows, const int* __restrict__ cols,
                          const float* __restrict__ vals,
                          const int* __restrict__ rowptr, int* __restrict__ fill,
                          int* __restrict__ colS, float* __restrict__ valS,
                          int E4, int E, int N)
{
  const int i = blockIdx.x * 256 + threadIdx.x;
  if (i >= E4) return;
  const int g = (i / E) * N + rows[i];
  const int p = rowptr[g] + atomicAdd(&fill[g], 1);
  colS[p] = cols[i];
  valS[p] = vals[i];
}

// ---------------- GAT attention scalars -------------------------------------
__global__ void k_att(const unsigned short* __restrict__ fself,
                      const float* __restrict__ a_s, const float* __restrict__ a_n,
                      float* __restrict__ attS, float* __restrict__ attN, int N)
{
  const int n = blockIdx.x * 4 + (threadIdx.x >> 6);
  if (n >= N) return;
  const int lane = threadIdx.x & 63;
  const ushort4 h = *(const ushort4*)(fself + (size_t)n * D + lane * 4);
  const float4 as = *(const float4*)(a_s + lane * 4);
  const float4 an = *(const float4*)(a_n + lane * 4);
  const float v0 = bf2f(h.x), v1 = bf2f(h.y), v2 = bf2f(h.z), v3 = bf2f(h.w);
  float ps = v0 * as.x + v1 * as.y + v2 * as.z + v3 * as.w;
  float pn = v0 * an.x + v1 * an.y + v2 * an.z + v3 * an.w;
#pragma unroll
  for (int off = 4; off >= 1; off >>= 1) {
    ps += __shfl_down(ps, off, 8);
    pn += __shfl_down(pn, off, 8);
  }
  if ((lane & 7) == 0) {
    const int hd = lane >> 3;
    attS[(size_t)n * NHEAD + hd] = (ps > 0.f) ? ps : 0.2f * ps;
    attN[(size_t)n * NHEAD + hd] = (pn > 0.f) ? pn : 0.2f * pn;
  }
}

// ---------------- Aggregations (one wave per node, CSR) ---------------------
__global__ void k_gat_agg(const unsigned short* __restrict__ fneigh,
                          const float* __restrict__ attS, const float* __restrict__ attN,
                          const int* __restrict__ rowptr, const int* __restrict__ colS,
                          const float* __restrict__ valS,
                          unsigned short* __restrict__ out, int N)
{
  const int n = blockIdx.x * 4 + (threadIdx.x >> 6);
  if (n >= N) return;
  const int lane = threadIdx.x & 63;
  const int head = lane >> 3;
  const float as = attS[(size_t)n * NHEAD + head];
  float a0 = 0.f, a1 = 0.f, a2 = 0.f, a3 = 0.f;
  const int s = rowptr[n], e = rowptr[n + 1];
  for (int p = s; p < e; ++p) {
    const int c   = colS[p];
    const float coef = (as + attN[(size_t)c * NHEAD + head]) * valS[p];
    const ushort4 f = *(const ushort4*)(fneigh + (size_t)c * D + lane * 4);
    a0 = fmaf(coef, bf2f(f.x), a0);
    a1 = fmaf(coef, bf2f(f.y), a1);
    a2 = fmaf(coef, bf2f(f.z), a2);
    a3 = fmaf(coef, bf2f(f.w), a3);
  }
  ushort4 o; o.x = f2bf(a0); o.y = f2bf(a1); o.z = f2bf(a2); o.w = f2bf(a3);
  *(ushort4*)(out + (size_t)n * D + lane * 4) = o;
}

__global__ void k_gcn_agg(const unsigned short* __restrict__ Hm,
                          const int* __restrict__ rowptr, const int* __restrict__ colS,
                          const float* __restrict__ valS,
                          unsigned short* __restrict__ out, int N)
{
  const int n = blockIdx.x * 4 + (threadIdx.x >> 6);
  if (n >= N) return;
  const int lane = threadIdx.x & 63;
  float a0 = 0.f, a1 = 0.f, a2 = 0.f, a3 = 0.f;
  const int s = rowptr[n], e = rowptr[n + 1];
  for (int p = s; p < e; ++p) {
    const int c = colS[p];
    const float v = valS[p];
    const ushort4 f = *(const ushort4*)(Hm + (size_t)c * D + lane * 4);
    a0 = fmaf(v, bf2f(f.x), a0);
    a1 = fmaf(v, bf2f(f.y), a1);
    a2 = fmaf(v, bf2f(f.z), a2);
    a3 = fmaf(v, bf2f(f.w), a3);
  }
  ushort4 o;                                   // relu before BN
  o.x = f2bf(fmaxf(a0, 0.f)); o.y = f2bf(fmaxf(a1, 0.f));
  o.z = f2bf(fmaxf(a2, 0.f)); o.w = f2bf(fmaxf(a3, 0.f));
  *(ushort4*)(out + (size_t)n * D + lane * 4) = o;
}

// ---------------- BatchNorm -------------------------------------------------
__global__ void k_bn_stats(const unsigned short* __restrict__ X, float* __restrict__ sums, int M)
{
  const int j = threadIdx.x;
  float s = 0.f, q = 0.f;
  for (int r = blockIdx.x; r < M; r += gridDim.x) {
    const float v = bf2f(X[(size_t)r * D + j]);
    s += v;
    q = fmaf(v, v, q);
  }
  atomicAdd(&sums[j], s);
  atomicAdd(&sums[D + j], q);
}

// finalize (in-LDS) + normalize, in-place bf16
__global__ void k_bn_norm(unsigned short* __restrict__ X, const float* __restrict__ sums, int M)
{
  __shared__ float mu[D], rs[D];
  const int t = threadIdx.x;
  {
    const float m_ = sums[t] / (float)M;
    const float v_ = sums[D + t] / (float)M - m_ * m_;
    mu[t] = m_;
    rs[t] = rsqrtf(v_ + BN_EPS);
  }
  __syncthreads();
  const size_t idx = (size_t)blockIdx.x * 256 + t;   // unit = 8 elems
  const int j0 = (int)((idx * 8) & (D - 1));
  uint4 raw = *(uint4*)(X + idx * 8);
  unsigned int w[4] = {raw.x, raw.y, raw.z, raw.w};
  uint4 o;
  unsigned int ov[4];
#pragma unroll
  for (int k = 0; k < 4; ++k) {
    const float lo = (bf2f((unsigned short)(w[k] & 0xffff)) - mu[j0 + 2 * k])     * rs[j0 + 2 * k];
    const float hi = (bf2f((unsigned short)(w[k] >> 16))    - mu[j0 + 2 * k + 1]) * rs[j0 + 2 * k + 1];
    ov[k] = (unsigned)f2bf(lo) | ((unsigned)f2bf(hi) << 16);
  }
  o.x = ov[0]; o.y = ov[1]; o.z = ov[2]; o.w = ov[3];
  *(uint4*)(X + idx * 8) = o;
}

// ---------------- Classifier ------------------------------------------------
__global__ void k_init_out(float* __restrict__ out, const float* __restrict__ cls_b, int n)
{
  const int i = blockIdx.x * 256 + threadIdx.x;
  if (i < n) out[i] = cls_b[i % NCLS];
}

__global__ void k_classifier(const unsigned short* __restrict__ F, const float* __restrict__ W,
                             float* __restrict__ out, int N, int baseRow)
{
  const int n = blockIdx.x * 4 + (threadIdx.x >> 6);
  if (n >= N) return;
  const int lane = threadIdx.x & 63;
  const ushort4 h = *(const ushort4*)(F + (size_t)n * D + lane * 4);
  const float f0 = bf2f(h.x), f1 = bf2f(h.y), f2 = bf2f(h.z), f3 = bf2f(h.w);
  const float* Wr = W + (size_t)(baseRow + lane * 4) * NCLS;
  float p[NCLS];
#pragma unroll
  for (int c = 0; c < NCLS; ++c)
    p[c] = f0 * Wr[c] + f1 * Wr[NCLS + c] + f2 * Wr[2 * NCLS + c] + f3 * Wr[3 * NCLS + c];
#pragma unroll
  for (int off = 32; off >= 1; off >>= 1)
#pragma unroll
    for (int c = 0; c < NCLS; ++c)
      p[c] += __shfl_down(p[c], off);
  if (lane == 0) {
    float* o = out + (size_t)n * NCLS;
#pragma unroll
    for (int c = 0; c < NCLS; ++c) o[c] += p[c];
  }
}

// ---------------------------------------------------------------------------
extern "C" void kernel_launch(void* const* d_in, const int* in_sizes, int n_in,
                              void* d_out, int out_size, void* d_ws, size_t ws_size,
                              hipStream_t stream)
{
  const float* f_in   = (const float*)d_in[0];
  const int*   erow   = (const int*)d_in[1];
  const int*   ecol   = (const int*)d_in[2];
  const float* eval   = (const float*)d_in[3];
  const float* gat_Ws = (const float*)d_in[4];
  const float* gat_bs = (const float*)d_in[5];
  const float* gat_Wn = (const float*)d_in[6];
  const float* gat_bn = (const float*)d_in[7];
  const float* gat_as = (const float*)d_in[8];
  const float* gat_an = (const float*)d_in[9];
  const float* gcn_W  = (const float*)d_in[10];
  const float* gcn_b  = (const float*)d_in[11];
  const float* self_W = (const float*)d_in[12];
  const float* self_b = (const float*)d_in[13];
  const float* cls_W  = (const float*)d_in[14];
  const float* cls_b  = (const float*)d_in[15];
  float* out = (float*)d_out;

  const int N  = in_sizes[0] / D;      // 50000
  const int E  = in_sizes[1] / 4;      // 400000
  const int E4 = 4 * E, N4 = 4 * N;
  const size_t ND = (size_t)N * D;

  // ---- workspace carve-up ----
  unsigned short* bufA = (unsigned short*)d_ws;
  unsigned short* bufB = bufA + ND;
  unsigned short* bufC = bufB + ND;
  unsigned short* finB = bufC + ND;
  unsigned short* Wt   = finB + ND;                 // 11*65536
  float* attS   = (float*)(Wt + (size_t)11 * D * D);
  float* attN   = attS + (size_t)N * NHEAD;
  int*   scanTmp= (int*)(attN + (size_t)N * NHEAD);
  int*   blkSum = scanTmp + N4;
  int*   rowptr = blkSum + 1024;
  int*   colS   = rowptr + (N4 + 4);
  float* valS   = (float*)(colS + E4);
  // zeroed region: cnt[4N] | fill[4N] | bnsums[9*512]
  int*   cnt    = (int*)(valS + E4);
  int*   fill   = cnt + N4;
  float* bnsums = (float*)(fill + N4);
  const size_t zero_bytes = (size_t)(2 * N4) * sizeof(int) + 9 * 2 * D * sizeof(float);

  const dim3 gemm_grid((N + 127) / 128, D / 128);
  const int nb4  = (N + 3) / 4;
  const int scanG = (N4 + 255) / 256;

  hipMemsetAsync(cnt, 0, zero_bytes, stream);

  // conversions
  k_cvt  <<<(int)(ND / 8 + 255) / 256, 256, 0, stream>>>(f_in, finB, (int)(ND / 8));
  k_cvt_w<<<11 * 256, 256, 0, stream>>>(gat_Ws, gat_Wn, gcn_W, self_W, Wt);

  // batched CSR for 4 adjacencies
  k_count   <<<(E4 + 255) / 256, 256, 0, stream>>>(erow, cnt, E4, E, N);
  k_scan_blk<<<scanG, 256, 0, stream>>>(cnt, scanTmp, blkSum, N4);
  k_scan_top<<<1, 1024, 0, stream>>>(blkSum, scanG);
  k_scan_fin<<<scanG, 256, 0, stream>>>(scanTmp, blkSum, rowptr, N4);
  k_scatter <<<(E4 + 255) / 256, 256, 0, stream>>>(erow, ecol, eval, rowptr, fill,
                                                   colS, valS, E4, E, N);

  k_init_out<<<(N * NCLS + 255) / 256, 256, 0, stream>>>(out, cls_b, N * NCLS);

  const size_t WM = (size_t)D * D;   // 65536 per matrix
  auto bn = [&](unsigned short* X, int id) {
    float* sums = bnsums + (size_t)id * 2 * D;
    k_bn_stats<<<512, 256, 0, stream>>>(X, sums, N);
    k_bn_norm <<<N / 8, 256, 0, stream>>>(X, sums, N);
  };

  // ===================== GAT branch (adjacency 0) ==========================
  {
    const int* rp = rowptr;            // adjacency 0
    // layer 0
    k_gemm_mfma<<<gemm_grid, 256, 0, stream>>>(finB, Wt + 0 * WM, gat_bs,     bufA, N, 1);
    k_att      <<<nb4, 256, 0, stream>>>(bufA, gat_as, gat_an, attS, attN, N);
    k_gemm_mfma<<<gemm_grid, 256, 0, stream>>>(finB, Wt + 1 * WM, gat_bn,     bufB, N, 1);
    k_gat_agg  <<<nb4, 256, 0, stream>>>(bufB, attS, attN, rp, colS, valS, bufC, N);
    bn(bufC, 0);
    // layer 1
    k_gemm_mfma<<<gemm_grid, 256, 0, stream>>>(bufC, Wt + 2 * WM, gat_bs + D, bufA, N, 1);
    k_att      <<<nb4, 256, 0, stream>>>(bufA, gat_as + D, gat_an + D, attS, attN, N);
    k_gemm_mfma<<<gemm_grid, 256, 0, stream>>>(bufC, Wt + 3 * WM, gat_bn + D, bufB, N, 1);
    k_gat_agg  <<<nb4, 256, 0, stream>>>(bufB, attS, attN, rp, colS, valS, bufA, N);
    bn(bufA, 1);
    k_classifier<<<nb4, 256, 0, stream>>>(bufA, cls_W, out, N, 0);
  }

  // ===================== 3 GCN branches (adjacency 1..3) ===================
  for (int g = 0; g < 3; ++g) {
    const int* rp = rowptr + (size_t)(g + 1) * N;
    const float* bg = gcn_b + (size_t)g * 2 * D;
    k_gemm_mfma<<<gemm_grid, 256, 0, stream>>>(finB, Wt + (4 + 2 * g) * WM, bg,     bufA, N, 0);
    k_gcn_agg  <<<nb4, 256, 0, stream>>>(bufA, rp, colS, valS, bufB, N);
    bn(bufB, 2 + 2 * g);
    k_gemm_mfma<<<gemm_grid, 256, 0, stream>>>(bufB, Wt + (5 + 2 * g) * WM, bg + D, bufA, N, 0);
    k_gcn_agg  <<<nb4, 256, 0, stream>>>(bufA, rp, colS, valS, bufB, N);
    bn(bufB, 3 + 2 * g);
    k_classifier<<<nb4, 256, 0, stream>>>(bufB, cls_W, out, N, (1 + g) * D);
  }

  // ===================== self perceptron ===================================
  k_gemm_mfma<<<gemm_grid, 256, 0, stream>>>(finB, Wt + 10 * WM, self_b, bufA, N, 1);
  bn(bufA, 8);
  k_classifier<<<nb4, 256, 0, stream>>>(bufA, cls_W, out, N, 4 * D);
}

// Round 3
// 1493.017 us; speedup vs baseline: 1.9682x; 1.0967x over previous
//
#include <hip/hip_runtime.h>

// ---------------------------------------------------------------------------
// ERC GNN forward — round 3:
//  * packed int2 edge scatter (1 store/edge instead of 2)
//  * GEMM staged via global_load_lds (16B), att fused into GAT-Ws epilogue
//  * 16B/lane gathers in agg/classifier (2 nodes per wave), vectorized BN stats
// ---------------------------------------------------------------------------

constexpr int D     = 256;
constexpr int NHEAD = 8;
constexpr int NCLS  = 7;
constexpr float BN_EPS = 1e-9f;

typedef short  s16x8 __attribute__((ext_vector_type(8)));
typedef float  f32x4 __attribute__((ext_vector_type(4)));

__device__ __forceinline__ unsigned short f2bf(float f) {
  unsigned int u = __builtin_bit_cast(unsigned int, f);
  u += 0x7FFFu + ((u >> 16) & 1u);          // round-to-nearest-even
  return (unsigned short)(u >> 16);
}
__device__ __forceinline__ float bf2f(unsigned short h) {
  unsigned int u = ((unsigned int)h) << 16;
  return __builtin_bit_cast(float, u);
}

__device__ __forceinline__ void gload_lds16(const void* g, void* l) {
  __builtin_amdgcn_global_load_lds(
      (const __attribute__((address_space(1))) unsigned int*)g,
      (__attribute__((address_space(3))) unsigned int*)l, 16, 0, 0);
}

// ---------------- bf16 MFMA GEMM: C[M,256] = A[M,256] @ Wt^T + bias ---------
// A bf16 [M,256]; Wt bf16 [256 cols][256 k]. 128x128 tile, 4 waves, 4x4 MFMA
// subtiles of 16x16x32. Staging: global_load_lds dwordx4, unpadded [128][32]
// LDS tiles (wave-uniform base + lane*16 — layout matches row-major tile).
// If attS!=null: fused GAT attention (leaky(relu(f)@a) per 32-col head).
__launch_bounds__(256)
__global__ void k_gemm_mfma(const unsigned short* __restrict__ A,
                            const unsigned short* __restrict__ Wt,
                            const float* __restrict__ bias,
                            unsigned short* __restrict__ C,
                            int M, int doRelu,
                            const float* __restrict__ a_s, const float* __restrict__ a_n,
                            float* __restrict__ attS, float* __restrict__ attN)
{
  __shared__ unsigned short As[128 * 32];
  __shared__ unsigned short Bs[128 * 32];
  const int t = threadIdx.x;
  const int wave = t >> 6, lane = t & 63;
  const int quad = lane >> 4, l16 = lane & 15;
  const int wm = (wave & 1) * 64, wn = (wave >> 1) * 64;
  const int bm = blockIdx.x * 128, bn = blockIdx.y * 128;

  f32x4 acc[4][4] = {};

  // chunk q = wave*2+i covers tile rows q*16..q*16+15; lane l -> row q*16+l/4,
  // k-offset (l&3)*8. LDS dest = chunk base + lane*16B (HW rule).
  const int rA0 = wave * 32 + (lane >> 2);
  const int rA1 = rA0 + 16;
  const int sub = (lane & 3) * 8;
  const unsigned short* gA0 = A  + (size_t)min(bm + rA0, M - 1) * D + sub;
  const unsigned short* gA1 = A  + (size_t)min(bm + rA1, M - 1) * D + sub;
  const unsigned short* gB0 = Wt + (size_t)(bn + rA0) * D + sub;
  const unsigned short* gB1 = Wt + (size_t)(bn + rA1) * D + sub;
  unsigned short* lA0 = &As[wave * 1024];
  unsigned short* lA1 = &As[wave * 1024 + 512];
  unsigned short* lB0 = &Bs[wave * 1024];
  unsigned short* lB1 = &Bs[wave * 1024 + 512];

  for (int k0 = 0; k0 < D; k0 += 32) {
    gload_lds16(gA0 + k0, lA0);
    gload_lds16(gA1 + k0, lA1);
    gload_lds16(gB0 + k0, lB0);
    gload_lds16(gB1 + k0, lB1);
    __syncthreads();
    s16x8 af[4], bf[4];
#pragma unroll
    for (int mi = 0; mi < 4; ++mi)
      af[mi] = *(const s16x8*)(&As[(wm + mi * 16 + l16) * 32 + quad * 8]);
#pragma unroll
    for (int nj = 0; nj < 4; ++nj)
      bf[nj] = *(const s16x8*)(&Bs[(wn + nj * 16 + l16) * 32 + quad * 8]);
#pragma unroll
    for (int mi = 0; mi < 4; ++mi)
#pragma unroll
      for (int nj = 0; nj < 4; ++nj)
        acc[mi][nj] = __builtin_amdgcn_mfma_f32_16x16x32_bf16(af[mi], bf[nj], acc[mi][nj], 0, 0, 0);
    __syncthreads();
  }

  // C/D layout: col = l16, row = quad*4 + reg (m89-verified)
  if (attS) {
    // GAT Ws path: relu always; head h spans cols [hb*32, +32) = 2 nj tiles,
    // entirely within this wave's 64-col span -> 16-lane reduction suffices.
    const int hb = (bn + wn) >> 5;
#pragma unroll
    for (int mi = 0; mi < 4; ++mi) {
#pragma unroll
      for (int h = 0; h < 2; ++h) {
        float ps[4] = {}, pn[4] = {};
#pragma unroll
        for (int j = 0; j < 2; ++j) {
          const int nj = h * 2 + j;
          const int col = bn + wn + nj * 16 + l16;
          const float bv = bias[col];
          const float av = a_s[col], nv = a_n[col];
#pragma unroll
          for (int r = 0; r < 4; ++r) {
            const int row = bm + wm + mi * 16 + quad * 4 + r;
            const float v = fmaxf(acc[mi][nj][r] + bv, 0.f);
            if (row < M) C[(size_t)row * D + col] = f2bf(v);
            ps[r] = fmaf(v, av, ps[r]);
            pn[r] = fmaf(v, nv, pn[r]);
          }
        }
#pragma unroll
        for (int m = 1; m < 16; m <<= 1)
#pragma unroll
          for (int r = 0; r < 4; ++r) {
            ps[r] += __shfl_xor(ps[r], m);
            pn[r] += __shfl_xor(pn[r], m);
          }
        if (l16 == 0) {
#pragma unroll
          for (int r = 0; r < 4; ++r) {
            const int row = bm + wm + mi * 16 + quad * 4 + r;
            if (row < M) {
              const float s_ = ps[r], n_ = pn[r];
              attS[(size_t)row * NHEAD + hb + h] = (s_ > 0.f) ? s_ : 0.2f * s_;
              attN[(size_t)row * NHEAD + hb + h] = (n_ > 0.f) ? n_ : 0.2f * n_;
            }
          }
        }
      }
    }
  } else {
#pragma unroll
    for (int nj = 0; nj < 4; ++nj) {
      const int col = bn + wn + nj * 16 + l16;
      const float bv = bias[col];
#pragma unroll
      for (int mi = 0; mi < 4; ++mi) {
#pragma unroll
        for (int r = 0; r < 4; ++r) {
          const int row = bm + wm + mi * 16 + quad * 4 + r;
          if (row < M) {
            float v = acc[mi][nj][r] + bv;
            if (doRelu) v = fmaxf(v, 0.f);
            C[(size_t)row * D + col] = f2bf(v);
          }
        }
      }
    }
  }
}

// ---------------- conversions -----------------------------------------------
__global__ void k_cvt(const float* __restrict__ src, unsigned short* __restrict__ dst, int n8)
{
  const int i = blockIdx.x * 256 + threadIdx.x;
  if (i >= n8) return;
  const float4 a = *(const float4*)(src + (size_t)i * 8);
  const float4 b = *(const float4*)(src + (size_t)i * 8 + 4);
  uint4 o;
  o.x = (unsigned)f2bf(a.x) | ((unsigned)f2bf(a.y) << 16);
  o.y = (unsigned)f2bf(a.z) | ((unsigned)f2bf(a.w) << 16);
  o.z = (unsigned)f2bf(b.x) | ((unsigned)f2bf(b.y) << 16);
  o.w = (unsigned)f2bf(b.z) | ((unsigned)f2bf(b.w) << 16);
  *(uint4*)(dst + (size_t)i * 8) = o;
}

__global__ void k_cvt_w(const float* __restrict__ gat_Ws, const float* __restrict__ gat_Wn,
                        const float* __restrict__ gcn_W, const float* __restrict__ self_W,
                        unsigned short* __restrict__ Wt)
{
  const int m = blockIdx.x >> 8, j = blockIdx.x & 255, d = threadIdx.x;
  float v;
  if (m < 4) {
    const int l = m >> 1;
    const float* W = (m & 1) ? gat_Wn : gat_Ws;          // [L,H,D,DH]
    v = W[(((size_t)l * NHEAD + (j >> 5)) * D + d) * 32 + (j & 31)];
  } else if (m < 10) {
    v = gcn_W[((size_t)(m - 4) * D + d) * D + j];         // [3*L,D,D]
  } else {
    v = self_W[(size_t)d * D + j];
  }
  Wt[((size_t)m * D + j) * D + d] = f2bf(v);
}

// ---------------- batched CSR build (4 adjacencies) --------------------------
__global__ void k_count(const int* __restrict__ rows, int* __restrict__ cnt, int E4, int E, int N)
{
  const int i = blockIdx.x * 256 + threadIdx.x;
  if (i < E4) atomicAdd(&cnt[(i / E) * N + rows[i]], 1);
}

__global__ void k_scan_blk(const int* __restrict__ in, int* __restrict__ scanTmp,
                           int* __restrict__ blkSum, int n)
{
  __shared__ int buf[256];
  const int t = threadIdx.x, i = blockIdx.x * 256 + t;
  const int v = (i < n) ? in[i] : 0;
  buf[t] = v; __syncthreads();
  for (int off = 1; off < 256; off <<= 1) {
    const int x = (t >= off) ? buf[t - off] : 0;
    __syncthreads();
    buf[t] += x; __syncthreads();
  }
  if (i < n) scanTmp[i] = buf[t];
  if (t == 255) blkSum[blockIdx.x] = buf[255];
}

__global__ void k_scan_top(int* __restrict__ blkSum, int G)
{
  __shared__ int buf[1024];
  const int t = threadIdx.x;
  const int v = (t < G) ? blkSum[t] : 0;
  buf[t] = v; __syncthreads();
  for (int off = 1; off < 1024; off <<= 1) {
    const int x = (t >= off) ? buf[t - off] : 0;
    __syncthreads();
    buf[t] += x; __syncthreads();
  }
  if (t < G) blkSum[t] = buf[t] - v;
}

__global__ void k_scan_fin(const int* __restrict__ scanTmp, const int* __restrict__ blkOff,
                           int* __restrict__ rowptr, int n)
{
  const int i = blockIdx.x * 256 + threadIdx.x;
  if (i < n) rowptr[i + 1] = scanTmp[i] + blkOff[blockIdx.x];
  if (i == 0) rowptr[0] = 0;
}

// packed scatter: one 8B store per edge {col, val-bits}
__global__ void k_scatter(const int* __restrict__ rows, const int* __restrict__ cols,
                          const float* __restrict__ vals,
                          const int* __restrict__ rowptr, int* __restrict__ fill,
                          int2* __restrict__ edge, int E4, int E, int N)
{
  const int i = blockIdx.x * 256 + threadIdx.x;
  if (i >= E4) return;
  const int g = (i / E) * N + rows[i];
  const int p = rowptr[g] + atomicAdd(&fill[g], 1);
  edge[p] = make_int2(cols[i], __float_as_int(vals[i]));
}

// ---------------- Aggregations: 2 nodes/wave, 16B gathers -------------------
__device__ __forceinline__ void acc8(float* a, uint4 f, float c) {
  const unsigned w[4] = {f.x, f.y, f.z, f.w};
#pragma unroll
  for (int k = 0; k < 4; ++k) {
    a[2 * k]     = fmaf(c, bf2f((unsigned short)(w[k] & 0xffff)), a[2 * k]);
    a[2 * k + 1] = fmaf(c, bf2f((unsigned short)(w[k] >> 16)),    a[2 * k + 1]);
  }
}

__device__ __forceinline__ uint4 pack8(const float* a, bool relu) {
  unsigned ov[4];
#pragma unroll
  for (int k = 0; k < 4; ++k) {
    float lo = a[2 * k], hi = a[2 * k + 1];
    if (relu) { lo = fmaxf(lo, 0.f); hi = fmaxf(hi, 0.f); }
    ov[k] = (unsigned)f2bf(lo) | ((unsigned)f2bf(hi) << 16);
  }
  uint4 o; o.x = ov[0]; o.y = ov[1]; o.z = ov[2]; o.w = ov[3];
  return o;
}

__global__ void k_gat_agg(const unsigned short* __restrict__ fneigh,
                          const float* __restrict__ attS, const float* __restrict__ attN,
                          const int* __restrict__ rowptr, const int2* __restrict__ edge,
                          unsigned short* __restrict__ out, int N)
{
  const int n = blockIdx.x * 8 + (threadIdx.x >> 5);
  if (n >= N) return;
  const int lane = threadIdx.x & 31;
  const int head = lane >> 2;                 // 8 cols/lane, 32 cols/head
  const float as = attS[(size_t)n * NHEAD + head];
  float a[8] = {};
  int p = rowptr[n];
  const int e = rowptr[n + 1];
  for (; p + 1 < e; p += 2) {
    const int2 e0 = edge[p], e1 = edge[p + 1];
    const float c0 = (as + attN[(size_t)e0.x * NHEAD + head]) * __int_as_float(e0.y);
    const float c1 = (as + attN[(size_t)e1.x * NHEAD + head]) * __int_as_float(e1.y);
    const uint4 f0 = *(const uint4*)(fneigh + (size_t)e0.x * D + lane * 8);
    const uint4 f1 = *(const uint4*)(fneigh + (size_t)e1.x * D + lane * 8);
    acc8(a, f0, c0);
    acc8(a, f1, c1);
  }
  if (p < e) {
    const int2 e0 = edge[p];
    const float c0 = (as + attN[(size_t)e0.x * NHEAD + head]) * __int_as_float(e0.y);
    const uint4 f0 = *(const uint4*)(fneigh + (size_t)e0.x * D + lane * 8);
    acc8(a, f0, c0);
  }
  *(uint4*)(out + (size_t)n * D + lane * 8) = pack8(a, false);
}

__global__ void k_gcn_agg(const unsigned short* __restrict__ Hm,
                          const int* __restrict__ rowptr, const int2* __restrict__ edge,
                          unsigned short* __restrict__ out, int N)
{
  const int n = blockIdx.x * 8 + (threadIdx.x >> 5);
  if (n >= N) return;
  const int lane = threadIdx.x & 31;
  float a[8] = {};
  int p = rowptr[n];
  const int e = rowptr[n + 1];
  for (; p + 1 < e; p += 2) {
    const int2 e0 = edge[p], e1 = edge[p + 1];
    const uint4 f0 = *(const uint4*)(Hm + (size_t)e0.x * D + lane * 8);
    const uint4 f1 = *(const uint4*)(Hm + (size_t)e1.x * D + lane * 8);
    acc8(a, f0, __int_as_float(e0.y));
    acc8(a, f1, __int_as_float(e1.y));
  }
  if (p < e) {
    const int2 e0 = edge[p];
    const uint4 f0 = *(const uint4*)(Hm + (size_t)e0.x * D + lane * 8);
    acc8(a, f0, __int_as_float(e0.y));
  }
  *(uint4*)(out + (size_t)n * D + lane * 8) = pack8(a, true);   // relu before BN
}

// ---------------- BatchNorm -------------------------------------------------
__launch_bounds__(256)
__global__ void k_bn_stats(const unsigned short* __restrict__ X, float* __restrict__ sums, int M)
{
  __shared__ float ls[256][8];
  __shared__ float lq[256][8];
  const int t = threadIdx.x, cg = t & 31, rg = t >> 5;
  float s[8] = {}, q[8] = {};
  for (int r = blockIdx.x * 8 + rg; r < M; r += gridDim.x * 8) {
    const uint4 f = *(const uint4*)(X + (size_t)r * D + cg * 8);
    const unsigned w[4] = {f.x, f.y, f.z, f.w};
#pragma unroll
    for (int k = 0; k < 4; ++k) {
      const float lo = bf2f((unsigned short)(w[k] & 0xffff));
      const float hi = bf2f((unsigned short)(w[k] >> 16));
      s[2 * k]     += lo; q[2 * k]     = fmaf(lo, lo, q[2 * k]);
      s[2 * k + 1] += hi; q[2 * k + 1] = fmaf(hi, hi, q[2 * k + 1]);
    }
  }
#pragma unroll
  for (int k = 0; k < 8; ++k) { ls[t][k] = s[k]; lq[t][k] = q[k]; }
  __syncthreads();
  if (rg == 0) {
#pragma unroll
    for (int g = 1; g < 8; ++g)
#pragma unroll
      for (int k = 0; k < 8; ++k) { s[k] += ls[cg + 32 * g][k]; q[k] += lq[cg + 32 * g][k]; }
#pragma unroll
    for (int k = 0; k < 8; ++k) {
      atomicAdd(&sums[cg * 8 + k], s[k]);
      atomicAdd(&sums[D + cg * 8 + k], q[k]);
    }
  }
}

__global__ void k_bn_norm(unsigned short* __restrict__ X, const float* __restrict__ sums, int M)
{
  __shared__ float mu[D], rs[D];
  const int t = threadIdx.x;
  {
    const float m_ = sums[t] / (float)M;
    const float v_ = sums[D + t] / (float)M - m_ * m_;
    mu[t] = m_;
    rs[t] = rsqrtf(v_ + BN_EPS);
  }
  __syncthreads();
  const size_t idx = (size_t)blockIdx.x * 256 + t;   // unit = 8 elems
  const int j0 = (int)((idx * 8) & (D - 1));
  uint4 raw = *(uint4*)(X + idx * 8);
  unsigned int w[4] = {raw.x, raw.y, raw.z, raw.w};
  unsigned int ov[4];
#pragma unroll
  for (int k = 0; k < 4; ++k) {
    const float lo = (bf2f((unsigned short)(w[k] & 0xffff)) - mu[j0 + 2 * k])     * rs[j0 + 2 * k];
    const float hi = (bf2f((unsigned short)(w[k] >> 16))    - mu[j0 + 2 * k + 1]) * rs[j0 + 2 * k + 1];
    ov[k] = (unsigned)f2bf(lo) | ((unsigned)f2bf(hi) << 16);
  }
  uint4 o; o.x = ov[0]; o.y = ov[1]; o.z = ov[2]; o.w = ov[3];
  *(uint4*)(X + idx * 8) = o;
}

// ---------------- Classifier ------------------------------------------------
__global__ void k_init_out(float* __restrict__ out, const float* __restrict__ cls_b, int n)
{
  const int i = blockIdx.x * 256 + threadIdx.x;
  if (i < n) out[i] = cls_b[i % NCLS];
}

__global__ void k_classifier(const unsigned short* __restrict__ F, const float* __restrict__ W,
                             float* __restrict__ out, int N, int baseRow)
{
  const int n = blockIdx.x * 8 + (threadIdx.x >> 5);
  if (n >= N) return;
  const int lane = threadIdx.x & 31;
  const uint4 f = *(const uint4*)(F + (size_t)n * D + lane * 8);
  const unsigned w[4] = {f.x, f.y, f.z, f.w};
  float fv[8];
#pragma unroll
  for (int k = 0; k < 4; ++k) {
    fv[2 * k]     = bf2f((unsigned short)(w[k] & 0xffff));
    fv[2 * k + 1] = bf2f((unsigned short)(w[k] >> 16));
  }
  const float* Wr = W + (size_t)(baseRow + lane * 8) * NCLS;
  float p[NCLS];
#pragma unroll
  for (int c = 0; c < NCLS; ++c) {
    float s = 0.f;
#pragma unroll
    for (int k = 0; k < 8; ++k) s = fmaf(fv[k], Wr[k * NCLS + c], s);
    p[c] = s;
  }
#pragma unroll
  for (int m = 1; m < 32; m <<= 1)
#pragma unroll
    for (int c = 0; c < NCLS; ++c) p[c] += __shfl_xor(p[c], m);
  if (lane == 0) {
    float* o = out + (size_t)n * NCLS;
#pragma unroll
    for (int c = 0; c < NCLS; ++c) o[c] += p[c];
  }
}

// ---------------------------------------------------------------------------
extern "C" void kernel_launch(void* const* d_in, const int* in_sizes, int n_in,
                              void* d_out, int out_size, void* d_ws, size_t ws_size,
                              hipStream_t stream)
{
  const float* f_in   = (const float*)d_in[0];
  const int*   erow   = (const int*)d_in[1];
  const int*   ecol   = (const int*)d_in[2];
  const float* eval   = (const float*)d_in[3];
  const float* gat_Ws = (const float*)d_in[4];
  const float* gat_bs = (const float*)d_in[5];
  const float* gat_Wn = (const float*)d_in[6];
  const float* gat_bn = (const float*)d_in[7];
  const float* gat_as = (const float*)d_in[8];
  const float* gat_an = (const float*)d_in[9];
  const float* gcn_W  = (const float*)d_in[10];
  const float* gcn_b  = (const float*)d_in[11];
  const float* self_W = (const float*)d_in[12];
  const float* self_b = (const float*)d_in[13];
  const float* cls_W  = (const float*)d_in[14];
  const float* cls_b  = (const float*)d_in[15];
  float* out = (float*)d_out;

  const int N  = in_sizes[0] / D;      // 50000
  const int E  = in_sizes[1] / 4;      // 400000
  const int E4 = 4 * E, N4 = 4 * N;
  const size_t ND = (size_t)N * D;

  // ---- workspace carve-up ----
  unsigned short* bufA = (unsigned short*)d_ws;
  unsigned short* bufB = bufA + ND;
  unsigned short* bufC = bufB + ND;
  unsigned short* finB = bufC + ND;
  unsigned short* Wt   = finB + ND;                 // 11*65536
  float* attS   = (float*)(Wt + (size_t)11 * D * D);
  float* attN   = attS + (size_t)N * NHEAD;
  int*   scanTmp= (int*)(attN + (size_t)N * NHEAD);
  int*   blkSum = scanTmp + N4;
  int*   rowptr = blkSum + 1024;
  int2*  edge   = (int2*)(rowptr + (N4 + 4));
  // zeroed region: cnt[4N] | fill[4N] | bnsums[9*512]
  int*   cnt    = (int*)(edge + E4);
  int*   fill   = cnt + N4;
  float* bnsums = (float*)(fill + N4);
  const size_t zero_bytes = (size_t)(2 * N4) * sizeof(int) + 9 * 2 * D * sizeof(float);

  const dim3 gemm_grid((N + 127) / 128, D / 128);
  const int nb8   = (N + 7) / 8;
  const int scanG = (N4 + 255) / 256;

  hipMemsetAsync(cnt, 0, zero_bytes, stream);

  // conversions
  k_cvt  <<<(int)(ND / 8 + 255) / 256, 256, 0, stream>>>(f_in, finB, (int)(ND / 8));
  k_cvt_w<<<11 * 256, 256, 0, stream>>>(gat_Ws, gat_Wn, gcn_W, self_W, Wt);

  // batched CSR for 4 adjacencies
  k_count   <<<(E4 + 255) / 256, 256, 0, stream>>>(erow, cnt, E4, E, N);
  k_scan_blk<<<scanG, 256, 0, stream>>>(cnt, scanTmp, blkSum, N4);
  k_scan_top<<<1, 1024, 0, stream>>>(blkSum, scanG);
  k_scan_fin<<<scanG, 256, 0, stream>>>(scanTmp, blkSum, rowptr, N4);
  k_scatter <<<(E4 + 255) / 256, 256, 0, stream>>>(erow, ecol, eval, rowptr, fill,
                                                   edge, E4, E, N);

  k_init_out<<<(N * NCLS + 255) / 256, 256, 0, stream>>>(out, cls_b, N * NCLS);

  const size_t WM = (size_t)D * D;
  auto bn = [&](unsigned short* X, int id) {
    float* sums = bnsums + (size_t)id * 2 * D;
    k_bn_stats<<<128, 256, 0, stream>>>(X, sums, N);
    k_bn_norm <<<(int)(ND / 8 / 256), 256, 0, stream>>>(X, sums, N);
  };

  // ===================== GAT branch (adjacency 0) ==========================
  {
    const int* rp = rowptr;
    // layer 0 (att fused into Ws GEMM epilogue)
    k_gemm_mfma<<<gemm_grid, 256, 0, stream>>>(finB, Wt + 0 * WM, gat_bs, bufA, N, 1,
                                               gat_as, gat_an, attS, attN);
    k_gemm_mfma<<<gemm_grid, 256, 0, stream>>>(finB, Wt + 1 * WM, gat_bn, bufB, N, 1,
                                               nullptr, nullptr, nullptr, nullptr);
    k_gat_agg  <<<nb8, 256, 0, stream>>>(bufB, attS, attN, rp, edge, bufC, N);
    bn(bufC, 0);
    // layer 1
    k_gemm_mfma<<<gemm_grid, 256, 0, stream>>>(bufC, Wt + 2 * WM, gat_bs + D, bufA, N, 1,
                                               gat_as + D, gat_an + D, attS, attN);
    k_gemm_mfma<<<gemm_grid, 256, 0, stream>>>(bufC, Wt + 3 * WM, gat_bn + D, bufB, N, 1,
                                               nullptr, nullptr, nullptr, nullptr);
    k_gat_agg  <<<nb8, 256, 0, stream>>>(bufB, attS, attN, rp, edge, bufA, N);
    bn(bufA, 1);
    k_classifier<<<nb8, 256, 0, stream>>>(bufA, cls_W, out, N, 0);
  }

  // ===================== 3 GCN branches (adjacency 1..3) ===================
  for (int g = 0; g < 3; ++g) {
    const int* rp = rowptr + (size_t)(g + 1) * N;
    const float* bg = gcn_b + (size_t)g * 2 * D;
    k_gemm_mfma<<<gemm_grid, 256, 0, stream>>>(finB, Wt + (4 + 2 * g) * WM, bg, bufA, N, 0,
                                               nullptr, nullptr, nullptr, nullptr);
    k_gcn_agg  <<<nb8, 256, 0, stream>>>(bufA, rp, edge, bufB, N);
    bn(bufB, 2 + 2 * g);
    k_gemm_mfma<<<gemm_grid, 256, 0, stream>>>(bufB, Wt + (5 + 2 * g) * WM, bg + D, bufA, N, 0,
                                               nullptr, nullptr, nullptr, nullptr);
    k_gcn_agg  <<<nb8, 256, 0, stream>>>(bufA, rp, edge, bufB, N);
    bn(bufB, 3 + 2 * g);
    k_classifier<<<nb8, 256, 0, stream>>>(bufB, cls_W, out, N, (1 + g) * D);
  }

  // ===================== self perceptron ===================================
  k_gemm_mfma<<<gemm_grid, 256, 0, stream>>>(finB, Wt + 10 * WM, self_b, bufA, N, 1,
                                             nullptr, nullptr, nullptr, nullptr);
  bn(bufA, 8);
  k_classifier<<<nb8, 256, 0, stream>>>(bufA, cls_W, out, N, 4 * D);
}